// Round 10
// baseline (307.213 us; speedup 1.0000x reference)
//
#include <hip/hip_runtime.h>

typedef _Float16 h8 __attribute__((ext_vector_type(8)));
typedef _Float16 h4 __attribute__((ext_vector_type(4)));
typedef float f4 __attribute__((ext_vector_type(4)));
typedef int i4v __attribute__((ext_vector_type(4)));

#define B_ 4096
#define T_ 64
#define I_ 8
#define H_ 128

// LDS layout (bytes). Total 147456 <= 163840.
#define WC0_OFF 0            // [512 packed-gates][128 k] fp16, 16-way XOR-swizzled
#define H0_OFF  131072       // 2 x [16 batch][128 u] fp16, swizzled
#define H1_OFF  139264       // 2 x [16][128]
#define LDS_TOTAL 147456

#define LOG2E    1.4426950408889634f
#define TWOLOG2E 2.8853900817779268f

__device__ __forceinline__ float sigm2_(float v) {
    return __builtin_amdgcn_rcpf(1.f + exp2f(-v));
}
__device__ __forceinline__ float tanh2_(float v) {
    return 1.f - 2.f * __builtin_amdgcn_rcpf(exp2f(v) + 1.f);
}
__device__ __forceinline__ float tanhn_(float v) {
    return 1.f - 2.f * __builtin_amdgcn_rcpf(exp2f(TWOLOG2E * v) + 1.f);
}
__device__ __forceinline__ int gs_of(int p) {
    return (p & 3) * H_ + (p >> 6) * 16 + ((p >> 2) & 3) * 4 + ((p >> 4) & 3);
}
__device__ __forceinline__ float scl_(int q) { return (q == 2) ? TWOLOG2E : LOG2E; }

// AGPR parking (r9-proven): allocator memory-spills arch overflow past 128,
// so Wc1's 128 regs live in the otherwise-idle AGPR half. ag_w once at init,
// volatile ag_r per use (volatile prevents loop-invariant hoisting back into
// arch regs). MFMAs stay builtins (r8: asm MFMAs destroyed regalloc).
__device__ __forceinline__ int ag_w(int v) {
    int r; asm volatile("v_accvgpr_write_b32 %0, %1" : "=a"(r) : "v"(v)); return r;
}
__device__ __forceinline__ int ag_r(int v) {
    int r; asm volatile("v_accvgpr_read_b32 %0, %1" : "=v"(r) : "a"(v)); return r;
}

// ROUND-10 STRUCTURE: one step computes L0(t) and L1(t-1) — fully independent
// (L1(t-1) needs h1(t-2) and h0(t-1), both final at entry). ONE barrier/step,
// 65 steps. L0(t) and L1(t-1) share the h0(t-1) B-fragments (read once).
// Buffers: h0 read buf (t+1)&1, write t&1; h1 read t&1, write (t+1)&1.
__global__ __launch_bounds__(512) void lstm_fused_kernel(
    const float* __restrict__ x,
    const float* __restrict__ Wih0, const float* __restrict__ Whh0,
    const float* __restrict__ bih0, const float* __restrict__ bhh0,
    const float* __restrict__ Wih1, const float* __restrict__ Whh1,
    const float* __restrict__ bih1, const float* __restrict__ bhh1,
    const float* __restrict__ Wd1, const float* __restrict__ bd1,
    const float* __restrict__ Wd2, const float* __restrict__ bd2,
    float* __restrict__ out)
{
    __shared__ __align__(16) unsigned char lds[LDS_TOTAL];
    const int tid = threadIdx.x;
    const int w   = tid >> 6;
    const int l   = tid & 63;
    const int c16 = l & 15;
    const int G4  = l >> 4;
    const int rowbase = blockIdx.x * 16;
    const int swzl = c16 << 4;          // 16-way key (row stride 256B = 16 slots)

    // ---- init: Wc0 (packed order, prescaled, fp16, swizzled) -> LDS
    {
        const int p  = tid;
        const int gs = gs_of(p);
        const float sc = scl_(p & 3);
        const float* src = Whh0 + (size_t)gs * H_;
        const int swz = (p & 15) << 4;
        unsigned char* dst = lds + WC0_OFF + p * 256;
#pragma unroll
        for (int kb = 0; kb < 16; kb++) {
            float4 f0 = *(const float4*)(src + kb * 8);
            float4 f1 = *(const float4*)(src + kb * 8 + 4);
            h8 v;
            v[0]=(_Float16)(f0.x*sc); v[1]=(_Float16)(f0.y*sc);
            v[2]=(_Float16)(f0.z*sc); v[3]=(_Float16)(f0.w*sc);
            v[4]=(_Float16)(f1.x*sc); v[5]=(_Float16)(f1.y*sc);
            v[6]=(_Float16)(f1.z*sc); v[7]=(_Float16)(f1.w*sc);
            *(h8*)(dst + ((kb * 16) ^ swz)) = v;
        }
    }
    // zero the t=0/t=1 read buffers (index 1 of each)
    {
        f4 z = {0.f, 0.f, 0.f, 0.f};
        if (tid < 256) *(f4*)(lds + H0_OFF + 4096 + tid * 16) = z;
        else           *(f4*)(lds + H1_OFF + 4096 + (tid - 256) * 16) = z;
    }

    // ---- init: Wc1 (all 32 frags, 128 regs) -> AGPR bank; ax; fp16 L1 bias
    int wag[128];                // constant-indexed only (full unroll)
    h4 ax16[4];
    h4 b1h[4];
    {
        const float sc1 = scl_(c16 & 3);
#pragma unroll
        for (int j = 0; j < 4; j++) {
            const int gs = gs_of(w * 64 + j * 16 + c16);
#pragma unroll
            for (int ks = 0; ks < 8; ks++) {
                const int k0 = ks * 32 + G4 * 8;
                const float* src = (k0 < 128) ? (Whh1 + (size_t)gs * H_ + k0)
                                              : (Wih1 + (size_t)gs * H_ + (k0 - 128));
                float4 f0 = *(const float4*)src;
                float4 f1 = *(const float4*)(src + 4);
                h8 v;
                v[0]=(_Float16)(f0.x*sc1); v[1]=(_Float16)(f0.y*sc1);
                v[2]=(_Float16)(f0.z*sc1); v[3]=(_Float16)(f0.w*sc1);
                v[4]=(_Float16)(f1.x*sc1); v[5]=(_Float16)(f1.y*sc1);
                v[6]=(_Float16)(f1.z*sc1); v[7]=(_Float16)(f1.w*sc1);
                i4v iv = *(i4v*)&v;
                wag[(j * 8 + ks) * 4 + 0] = ag_w(iv[0]);
                wag[(j * 8 + ks) * 4 + 1] = ag_w(iv[1]);
                wag[(j * 8 + ks) * 4 + 2] = ag_w(iv[2]);
                wag[(j * 8 + ks) * 4 + 3] = ag_w(iv[3]);
            }
            h4 a;
#pragma unroll
            for (int e = 0; e < 4; e++) {
                const int k = G4 * 4 + e;
                float val = 0.f;
                if (k < 8)       val = Wih0[(size_t)gs * I_ + k] * sc1;
                else if (k == 8) val = (bih0[gs] + bhh0[gs]) * sc1;
                a[e] = (_Float16)val;
            }
            ax16[j] = a;
#pragma unroll
            for (int q2 = 0; q2 < 4; q2++) {
                const int gs2 = q2 * H_ + w * 16 + G4 * 4 + j;
                b1h[j][q2] = (_Float16)((bih1[gs2] + bhh1[gs2]) * scl_(q2));
            }
        }
    }

    const float* xrow = x + (size_t)(rowbase + c16) * T_ * I_;
    float4 xf0 = *(const float4*)(xrow);
    float4 xf1 = *(const float4*)(xrow + 4);

    float c0r[4] = {0.f, 0.f, 0.f, 0.f};
    float c1r[4] = {0.f, 0.f, 0.f, 0.f};

    __syncthreads();

    int cur = 0;                 // == t & 1
    for (int t = 0; t <= T_; t++) {
        const bool doL0 = (t < T_);
        const bool doL1 = (t > 0);

        // ---- B-fragments. b0 = h0(t-1): used by BOTH L0(t) and L1(t-1).
        h8 b0[4], b1f[4];
        const unsigned char* h0rd = lds + H0_OFF + (cur ^ 1) * 4096;
#pragma unroll
        for (int ks = 0; ks < 4; ks++)
            b0[ks] = *(const h8*)(h0rd + ((c16 * 256 + ks * 64 + G4 * 16) ^ swzl));
        if (doL1) {
            const unsigned char* h1rd = lds + H1_OFF + cur * 4096;
#pragma unroll
            for (int ks = 0; ks < 4; ks++)
                b1f[ks] = *(const h8*)(h1rd + ((c16 * 256 + ks * 64 + G4 * 16) ^ swzl));
        }

        // ---- x/bias B-frag (K=16): k<8 = x_t, k=8 -> 1.0
        h4 bx;
        bx[0] = (_Float16)0.f; bx[1] = (_Float16)0.f;
        bx[2] = (_Float16)0.f; bx[3] = (_Float16)0.f;
        if (G4 == 0) {
            bx[0]=(_Float16)xf0.x; bx[1]=(_Float16)xf0.y;
            bx[2]=(_Float16)xf0.z; bx[3]=(_Float16)xf0.w;
        } else if (G4 == 1) {
            bx[0]=(_Float16)xf1.x; bx[1]=(_Float16)xf1.y;
            bx[2]=(_Float16)xf1.z; bx[3]=(_Float16)xf1.w;
        } else if (G4 == 2) {
            bx[0] = (_Float16)1.f;
        }
        if (t < T_ - 1) {
            xf0 = *(const float4*)(xrow + (t + 1) * 8);
            xf1 = *(const float4*)(xrow + (t + 1) * 8 + 4);
        }

        f4 acc0[4], acc1[4];
        // ---------------- L0(t): Wc0 (LDS) @ h0(t-1) + Wx @ [x_t|1]
        if (doL0) {
            {
                f4 z = {0.f, 0.f, 0.f, 0.f};
#pragma unroll
                for (int j = 0; j < 4; j++) acc0[j] = z;
            }
#pragma unroll
            for (int ks = 0; ks < 4; ks++) {
#pragma unroll
                for (int j = 0; j < 4; j++) {
                    h8 a = *(const h8*)(lds + WC0_OFF + (w * 64 + j * 16 + c16) * 256
                                        + ((ks * 64 + G4 * 16) ^ swzl));
                    acc0[j] = __builtin_amdgcn_mfma_f32_16x16x32_f16(a, b0[ks], acc0[j], 0, 0, 0);
                }
            }
#pragma unroll
            for (int j = 0; j < 4; j++)
                acc0[j] = __builtin_amdgcn_mfma_f32_16x16x16f16(ax16[j], bx, acc0[j], 0, 0, 0);
        }

        // ---------------- L1(t-1): Wc1 (AGPR) @ [h1(t-2) | h0(t-1)]
        if (doL1) {
            {
                f4 z = {0.f, 0.f, 0.f, 0.f};
#pragma unroll
                for (int j = 0; j < 4; j++) acc1[j] = z;
            }
#pragma unroll
            for (int ks = 0; ks < 4; ks++) {          // hh half: b = h1(t-2)
#pragma unroll
                for (int j = 0; j < 4; j++) {
                    i4v iv;
                    iv[0] = ag_r(wag[(j * 8 + ks) * 4 + 0]);
                    iv[1] = ag_r(wag[(j * 8 + ks) * 4 + 1]);
                    iv[2] = ag_r(wag[(j * 8 + ks) * 4 + 2]);
                    iv[3] = ag_r(wag[(j * 8 + ks) * 4 + 3]);
                    h8 a = *(h8*)&iv;
                    acc1[j] = __builtin_amdgcn_mfma_f32_16x16x32_f16(a, b1f[ks], acc1[j], 0, 0, 0);
                }
            }
#pragma unroll
            for (int ks = 0; ks < 4; ks++) {          // ih half: b = h0(t-1), shared with L0
#pragma unroll
                for (int j = 0; j < 4; j++) {
                    i4v iv;
                    iv[0] = ag_r(wag[(j * 8 + 4 + ks) * 4 + 0]);
                    iv[1] = ag_r(wag[(j * 8 + 4 + ks) * 4 + 1]);
                    iv[2] = ag_r(wag[(j * 8 + 4 + ks) * 4 + 2]);
                    iv[3] = ag_r(wag[(j * 8 + 4 + ks) * 4 + 3]);
                    h8 a = *(h8*)&iv;
                    acc1[j] = __builtin_amdgcn_mfma_f32_16x16x32_f16(a, b0[ks], acc1[j], 0, 0, 0);
                }
            }
        }

        // ---------------- epilogues (independent; compiler interleaves)
        if (doL0) {
            unsigned char* h0wr = lds + H0_OFF + cur * 4096;
            h4 hv;
#pragma unroll
            for (int j = 0; j < 4; j++) {
                const float vi = sigm2_(acc0[j][0]);
                const float vf = sigm2_(acc0[j][1]);
                const float vg = tanh2_(acc0[j][2]);
                const float vo = sigm2_(acc0[j][3]);
                const float cn = vf * c0r[j] + vi * vg;
                c0r[j] = cn;
                hv[j] = (_Float16)(vo * tanhn_(cn));
            }
            *(h4*)(h0wr + ((c16 * 256 + w * 32 + G4 * 8) ^ swzl)) = hv;
        }
        if (doL1) {
            unsigned char* h1wr = lds + H1_OFF + (cur ^ 1) * 4096;
            h4 hv;
#pragma unroll
            for (int j = 0; j < 4; j++) {
                const float vi = sigm2_(acc1[j][0] + (float)b1h[j][0]);
                const float vf = sigm2_(acc1[j][1] + (float)b1h[j][1]);
                const float vg = tanh2_(acc1[j][2] + (float)b1h[j][2]);
                const float vo = sigm2_(acc1[j][3] + (float)b1h[j][3]);
                const float cn = vf * c1r[j] + vi * vg;
                c1r[j] = cn;
                hv[j] = (_Float16)(vo * tanhn_(cn));
            }
            *(h4*)(h1wr + ((c16 * 256 + w * 32 + G4 * 8) ^ swzl)) = hv;
        }

        __syncthreads();        // single barrier per step
        cur ^= 1;
    }

    // ---------------- head (h1(63) written at t=64 into buffer 1)
    if (tid < 128) {
        const int r = tid >> 3, part = tid & 7;
        const unsigned char* h1f = lds + H1_OFF + 4096;
        const int rswz = r << 4;
        float s0 = 0.f, s1 = 0.f, s2 = 0.f, s3 = 0.f, s4 = 0.f;
#pragma unroll
        for (int kk = 0; kk < 16; kk++) {
            const int k = part * 16 + kk;
            float a = (float)*(const _Float16*)(h1f + ((r * 256 + k * 2) ^ rswz));
            a = fmaxf(a, 0.f);
            s0 += a * Wd1[0 * H_ + k];
            s1 += a * Wd1[1 * H_ + k];
            s2 += a * Wd1[2 * H_ + k];
            s3 += a * Wd1[3 * H_ + k];
            s4 += a * Wd1[4 * H_ + k];
        }
#pragma unroll
        for (int m = 1; m < 8; m <<= 1) {
            s0 += __shfl_xor(s0, m);
            s1 += __shfl_xor(s1, m);
            s2 += __shfl_xor(s2, m);
            s3 += __shfl_xor(s3, m);
            s4 += __shfl_xor(s4, m);
        }
        if (part == 0) {
            float o = bd2[0];
            o += fmaxf(s0 + bd1[0], 0.f) * Wd2[0];
            o += fmaxf(s1 + bd1[1], 0.f) * Wd2[1];
            o += fmaxf(s2 + bd1[2], 0.f) * Wd2[2];
            o += fmaxf(s3 + bd1[3], 0.f) * Wd2[3];
            o += fmaxf(s4 + bd1[4], 0.f) * Wd2[4];
            out[rowbase + r] = o;
        }
    }
}

extern "C" void kernel_launch(void* const* d_in, const int* in_sizes, int n_in,
                              void* d_out, int out_size, void* d_ws, size_t ws_size,
                              hipStream_t stream)
{
    const float* x    = (const float*)d_in[0];
    const float* Wih0 = (const float*)d_in[1];
    const float* Whh0 = (const float*)d_in[2];
    const float* bih0 = (const float*)d_in[3];
    const float* bhh0 = (const float*)d_in[4];
    const float* Wih1 = (const float*)d_in[5];
    const float* Whh1 = (const float*)d_in[6];
    const float* bih1 = (const float*)d_in[7];
    const float* bhh1 = (const float*)d_in[8];
    const float* Wd1  = (const float*)d_in[9];
    const float* bd1  = (const float*)d_in[10];
    const float* Wd2  = (const float*)d_in[11];
    const float* bd2  = (const float*)d_in[12];

    lstm_fused_kernel<<<B_ / 16, 512, 0, stream>>>(
        x, Wih0, Whh0, bih0, bhh0, Wih1, Whh1, bih1, bhh1,
        Wd1, bd1, Wd2, bd2, (float*)d_out);
}

// Round 11
// 223.490 us; speedup vs baseline: 1.3746x; 1.3746x over previous
//
#include <hip/hip_runtime.h>

typedef _Float16 h8 __attribute__((ext_vector_type(8)));
typedef _Float16 h4 __attribute__((ext_vector_type(4)));
typedef _Float16 h2 __attribute__((ext_vector_type(2)));
typedef float f4 __attribute__((ext_vector_type(4)));
typedef int i4v __attribute__((ext_vector_type(4)));

#define B_ 4096
#define T_ 64
#define I_ 8
#define H_ 128

// LDS layout (bytes). Total 147456 <= 163840. 1 block/CU, 16 waves = 4/SIMD.
#define WC0_OFF 0            // [512 packed-gates][128 k] fp16, 16-way XOR-swizzled
#define H0_OFF  131072       // 2 x [16 batch][128 u] fp16, swizzled
#define H1_OFF  139264       // 2 x [16][128]
#define LDS_TOTAL 147456

#define LOG2E    1.4426950408889634f
#define TWOLOG2E 2.8853900817779268f

__device__ __forceinline__ float sigm2_(float v) {
    return __builtin_amdgcn_rcpf(1.f + exp2f(-v));
}
__device__ __forceinline__ float tanh2_(float v) {
    return 1.f - 2.f * __builtin_amdgcn_rcpf(exp2f(v) + 1.f);
}
__device__ __forceinline__ float tanhn_(float v) {
    return 1.f - 2.f * __builtin_amdgcn_rcpf(exp2f(TWOLOG2E * v) + 1.f);
}
// 16-wave packed order: p = w*32 + j*16 + G4*4 + q -> u = w*8 + G4*2 + j,
// original row gs = q*H + u  (j in {0,1})
__device__ __forceinline__ int gs16_(int p) {
    return (p & 3) * H_ + (p >> 5) * 8 + ((p >> 2) & 3) * 2 + ((p >> 4) & 1);
}
__device__ __forceinline__ float scl_(int q) { return (q == 2) ? TWOLOG2E : LOG2E; }

// AGPR parking (r9-proven). At 1024 thr the unified file splits 64 arch + 64
// acc per wave; Wc1's 16 frags = exactly 64 AGPRs. ag_w once, volatile ag_r
// per use. MFMAs stay builtins (r8: asm MFMAs wreck regalloc).
__device__ __forceinline__ int ag_w(int v) {
    int r; asm volatile("v_accvgpr_write_b32 %0, %1" : "=a"(r) : "v"(v)); return r;
}
__device__ __forceinline__ int ag_r(int v) {
    int r; asm volatile("v_accvgpr_read_b32 %0, %1" : "=v"(r) : "a"(v)); return r;
}

// x -> fp16 once (kills the per-thread float4 prefetch registers in the main loop)
__global__ __launch_bounds__(256) void prep_x(
    const float* __restrict__ x, _Float16* __restrict__ xh)
{
    const int i = (blockIdx.x * 256 + threadIdx.x) * 4;
    float4 v = *(const float4*)(x + i);
    h4 o;
    o[0] = (_Float16)v.x; o[1] = (_Float16)v.y;
    o[2] = (_Float16)v.z; o[3] = (_Float16)v.w;
    *(h4*)(xh + i) = o;
}

// r10 dataflow (one barrier/step, 65 steps: L0(t) || L1(t-1), shared h0 reads)
// at 16 waves: j=2 per thread. B-frags consumed inside the ks loop (4 live
// regs, not 16) to hold arch demand ~54 < 64.
__global__ __launch_bounds__(1024) void lstm_fused_kernel(
    const _Float16* __restrict__ xh,
    const float* __restrict__ Wih0, const float* __restrict__ Whh0,
    const float* __restrict__ bih0, const float* __restrict__ bhh0,
    const float* __restrict__ Wih1, const float* __restrict__ Whh1,
    const float* __restrict__ bih1, const float* __restrict__ bhh1,
    const float* __restrict__ Wd1, const float* __restrict__ bd1,
    const float* __restrict__ Wd2, const float* __restrict__ bd2,
    float* __restrict__ out)
{
    __shared__ __align__(16) unsigned char lds[LDS_TOTAL];
    const int tid = threadIdx.x;
    const int w   = tid >> 6;          // 0..15
    const int l   = tid & 63;
    const int c16 = l & 15;
    const int G4  = l >> 4;
    const int rowbase = blockIdx.x * 16;
    const int swzl = c16 << 4;         // 16-way key (row stride 256B = 16 slots)

    // ---- Wc0 (packed, prescaled, swizzled) -> LDS; 2 threads per row
    {
        const int p    = tid >> 1;
        const int half = tid & 1;
        const int gs   = gs16_(p);
        const float sc = scl_(p & 3);
        const float* src = Whh0 + (size_t)gs * H_;
        const int swz = (p & 15) << 4;
        unsigned char* dst = lds + WC0_OFF + p * 256;
#pragma unroll
        for (int kk = 0; kk < 8; kk++) {
            const int kb = half * 8 + kk;
            float4 f0 = *(const float4*)(src + kb * 8);
            float4 f1 = *(const float4*)(src + kb * 8 + 4);
            h8 v;
            v[0]=(_Float16)(f0.x*sc); v[1]=(_Float16)(f0.y*sc);
            v[2]=(_Float16)(f0.z*sc); v[3]=(_Float16)(f0.w*sc);
            v[4]=(_Float16)(f1.x*sc); v[5]=(_Float16)(f1.y*sc);
            v[6]=(_Float16)(f1.z*sc); v[7]=(_Float16)(f1.w*sc);
            *(h8*)(dst + ((kb * 16) ^ swz)) = v;
        }
    }
    // zero the t=0 read buffers (index 1)
    {
        f4 z = {0.f, 0.f, 0.f, 0.f};
        if (tid < 256)      *(f4*)(lds + H0_OFF + 4096 + tid * 16) = z;
        else if (tid < 512) *(f4*)(lds + H1_OFF + 4096 + (tid - 256) * 16) = z;
    }

    // ---- Wc1 (16 frags = 64 regs) -> AGPR; ax frag; fp16 L1 bias
    int wag[64];                       // constant-indexed only
    h4 ax16[2];
    h4 b1h[2];
    {
        const float sc1 = scl_(c16 & 3);
#pragma unroll
        for (int j = 0; j < 2; j++) {
            const int gs = gs16_(w * 32 + j * 16 + c16);
#pragma unroll
            for (int ks = 0; ks < 8; ks++) {
                const int k0 = ks * 32 + G4 * 8;
                const float* src = (k0 < 128) ? (Whh1 + (size_t)gs * H_ + k0)
                                              : (Wih1 + (size_t)gs * H_ + (k0 - 128));
                float4 f0 = *(const float4*)src;
                float4 f1 = *(const float4*)(src + 4);
                h8 v;
                v[0]=(_Float16)(f0.x*sc1); v[1]=(_Float16)(f0.y*sc1);
                v[2]=(_Float16)(f0.z*sc1); v[3]=(_Float16)(f0.w*sc1);
                v[4]=(_Float16)(f1.x*sc1); v[5]=(_Float16)(f1.y*sc1);
                v[6]=(_Float16)(f1.z*sc1); v[7]=(_Float16)(f1.w*sc1);
                i4v iv = *(i4v*)&v;
                wag[(j * 8 + ks) * 4 + 0] = ag_w(iv[0]);
                wag[(j * 8 + ks) * 4 + 1] = ag_w(iv[1]);
                wag[(j * 8 + ks) * 4 + 2] = ag_w(iv[2]);
                wag[(j * 8 + ks) * 4 + 3] = ag_w(iv[3]);
            }
            h4 a;
#pragma unroll
            for (int e = 0; e < 4; e++) {
                const int k = G4 * 4 + e;
                float val = 0.f;
                if (k < 8)       val = Wih0[(size_t)gs * I_ + k] * sc1;
                else if (k == 8) val = (bih0[gs] + bhh0[gs]) * sc1;
                a[e] = (_Float16)val;
            }
            ax16[j] = a;
#pragma unroll
            for (int q2 = 0; q2 < 4; q2++) {
                const int gs2 = q2 * H_ + w * 8 + G4 * 2 + j;
                b1h[j][q2] = (_Float16)((bih1[gs2] + bhh1[gs2]) * scl_(q2));
            }
        }
    }

    const _Float16* xrow = xh + (size_t)(rowbase + c16) * T_ * I_;
    h4 xn;
    if (G4 < 2) xn = *(const h4*)(xrow + G4 * 4);     // t=0 prefetch

    float c0r[2] = {0.f, 0.f};
    float c1r[2] = {0.f, 0.f};
    const f4 fz = {0.f, 0.f, 0.f, 0.f};

    __syncthreads();

    int cur = 0;                       // == t & 1
    for (int t = 0; t <= T_; t++) {
        const bool doL0 = (t < T_);
        const bool doL1 = (t > 0);

        // x/bias B-frag (K=16): k<8 = x_t, k=8 -> 1.0
        h4 bx;
        bx[0] = (_Float16)0.f; bx[1] = (_Float16)0.f;
        bx[2] = (_Float16)0.f; bx[3] = (_Float16)0.f;
        if (G4 < 2) bx = xn;
        else if (G4 == 2) bx[0] = (_Float16)1.f;
        if (t < T_ - 1 && G4 < 2)
            xn = *(const h4*)(xrow + (t + 1) * I_ + G4 * 4);

        const unsigned char* h0rd = lds + H0_OFF + (cur ^ 1) * 4096;
        const unsigned char* h1rd = lds + H1_OFF + cur * 4096;

        f4 acc0[2], acc1[2];
        if (doL0) {
#pragma unroll
            for (int j = 0; j < 2; j++)   // start chain from fz: no acc zero-movs
                acc0[j] = __builtin_amdgcn_mfma_f32_16x16x16f16(ax16[j], bx, fz, 0, 0, 0);
        }
        // shared-b0 loop: L0 hh-half and L1 ih-half both consume h0(t-1)
#pragma unroll
        for (int ks = 0; ks < 4; ks++) {
            h8 b0k = *(const h8*)(h0rd + ((c16 * 256 + ks * 64 + G4 * 16) ^ swzl));
            if (doL0) {
#pragma unroll
                for (int j = 0; j < 2; j++) {
                    h8 a = *(const h8*)(lds + WC0_OFF + (w * 32 + j * 16 + c16) * 256
                                        + ((ks * 64 + G4 * 16) ^ swzl));
                    acc0[j] = __builtin_amdgcn_mfma_f32_16x16x32_f16(a, b0k, acc0[j], 0, 0, 0);
                }
            }
#pragma unroll
            for (int j = 0; j < 2; j++) {
                i4v iv;
                iv[0] = ag_r(wag[(j * 8 + 4 + ks) * 4 + 0]);
                iv[1] = ag_r(wag[(j * 8 + 4 + ks) * 4 + 1]);
                iv[2] = ag_r(wag[(j * 8 + 4 + ks) * 4 + 2]);
                iv[3] = ag_r(wag[(j * 8 + 4 + ks) * 4 + 3]);
                h8 a = *(h8*)&iv;
                acc1[j] = __builtin_amdgcn_mfma_f32_16x16x32_f16(
                    a, b0k, (ks == 0) ? fz : acc1[j], 0, 0, 0);
            }
        }
        if (doL1) {
#pragma unroll
            for (int ks = 0; ks < 4; ks++) {
                h8 b1k = *(const h8*)(h1rd + ((c16 * 256 + ks * 64 + G4 * 16) ^ swzl));
#pragma unroll
                for (int j = 0; j < 2; j++) {
                    i4v iv;
                    iv[0] = ag_r(wag[(j * 8 + ks) * 4 + 0]);
                    iv[1] = ag_r(wag[(j * 8 + ks) * 4 + 1]);
                    iv[2] = ag_r(wag[(j * 8 + ks) * 4 + 2]);
                    iv[3] = ag_r(wag[(j * 8 + ks) * 4 + 3]);
                    h8 a = *(h8*)&iv;
                    acc1[j] = __builtin_amdgcn_mfma_f32_16x16x32_f16(a, b1k, acc1[j], 0, 0, 0);
                }
            }
        }

        // epilogues
        if (doL0) {
            unsigned char* h0wr = lds + H0_OFF + cur * 4096;
            h2 hv;
#pragma unroll
            for (int j = 0; j < 2; j++) {
                const float vi = sigm2_(acc0[j][0]);
                const float vf = sigm2_(acc0[j][1]);
                const float vg = tanh2_(acc0[j][2]);
                const float vo = sigm2_(acc0[j][3]);
                const float cn = vf * c0r[j] + vi * vg;
                c0r[j] = cn;
                hv[j] = (_Float16)(vo * tanhn_(cn));
            }
            *(h2*)(h0wr + ((c16 * 256 + w * 16 + G4 * 4) ^ swzl)) = hv;
        }
        if (doL1) {
            unsigned char* h1wr = lds + H1_OFF + (cur ^ 1) * 4096;
            h2 hv;
#pragma unroll
            for (int j = 0; j < 2; j++) {
                const float vi = sigm2_(acc1[j][0] + (float)b1h[j][0]);
                const float vf = sigm2_(acc1[j][1] + (float)b1h[j][1]);
                const float vg = tanh2_(acc1[j][2] + (float)b1h[j][2]);
                const float vo = sigm2_(acc1[j][3] + (float)b1h[j][3]);
                const float cn = vf * c1r[j] + vi * vg;
                c1r[j] = cn;
                hv[j] = (_Float16)(vo * tanhn_(cn));
            }
            *(h2*)(h1wr + ((c16 * 256 + w * 16 + G4 * 4) ^ swzl)) = hv;
        }

        __syncthreads();               // single barrier per step
        cur ^= 1;
    }

    // ---- head (h1(63) written at t=64 into buffer 1)
    if (tid < 128) {
        const int r = tid >> 3, part = tid & 7;
        const unsigned char* h1f = lds + H1_OFF + 4096;
        const int rswz = r << 4;
        float s0 = 0.f, s1 = 0.f, s2 = 0.f, s3 = 0.f, s4 = 0.f;
#pragma unroll
        for (int kk = 0; kk < 16; kk++) {
            const int k = part * 16 + kk;
            float a = (float)*(const _Float16*)(h1f + ((r * 256 + k * 2) ^ rswz));
            a = fmaxf(a, 0.f);
            s0 += a * Wd1[0 * H_ + k];
            s1 += a * Wd1[1 * H_ + k];
            s2 += a * Wd1[2 * H_ + k];
            s3 += a * Wd1[3 * H_ + k];
            s4 += a * Wd1[4 * H_ + k];
        }
#pragma unroll
        for (int m = 1; m < 8; m <<= 1) {
            s0 += __shfl_xor(s0, m);
            s1 += __shfl_xor(s1, m);
            s2 += __shfl_xor(s2, m);
            s3 += __shfl_xor(s3, m);
            s4 += __shfl_xor(s4, m);
        }
        if (part == 0) {
            float o = bd2[0];
            o += fmaxf(s0 + bd1[0], 0.f) * Wd2[0];
            o += fmaxf(s1 + bd1[1], 0.f) * Wd2[1];
            o += fmaxf(s2 + bd1[2], 0.f) * Wd2[2];
            o += fmaxf(s3 + bd1[3], 0.f) * Wd2[3];
            o += fmaxf(s4 + bd1[4], 0.f) * Wd2[4];
            out[rowbase + r] = o;
        }
    }
}

extern "C" void kernel_launch(void* const* d_in, const int* in_sizes, int n_in,
                              void* d_out, int out_size, void* d_ws, size_t ws_size,
                              hipStream_t stream)
{
    const float* x    = (const float*)d_in[0];
    const float* Wih0 = (const float*)d_in[1];
    const float* Whh0 = (const float*)d_in[2];
    const float* bih0 = (const float*)d_in[3];
    const float* bhh0 = (const float*)d_in[4];
    const float* Wih1 = (const float*)d_in[5];
    const float* Whh1 = (const float*)d_in[6];
    const float* bih1 = (const float*)d_in[7];
    const float* bhh1 = (const float*)d_in[8];
    const float* Wd1  = (const float*)d_in[9];
    const float* bd1  = (const float*)d_in[10];
    const float* Wd2  = (const float*)d_in[11];
    const float* bd2  = (const float*)d_in[12];

    _Float16* xh = (_Float16*)d_ws;    // 4 MB

    prep_x<<<(B_ * T_ * I_) / 1024, 256, 0, stream>>>(x, xh);

    lstm_fused_kernel<<<B_ / 16, 1024, 0, stream>>>(
        xh, Wih0, Whh0, bih0, bhh0, Wih1, Whh1, bih1, bhh1,
        Wd1, bd1, Wd2, bd2, (float*)d_out);
}